// Round 2
// 112.371 us; speedup vs baseline: 1.0152x; 1.0152x over previous
//
#include <hip/hip_runtime.h>

#define DXYZ 128
#define NVERT (DXYZ * DXYZ * DXYZ)     // 2097152 voxels per (cloud,batch) grid
#define SBINS 128                       // bins per grid: 16(x) x 8(y), full z
#define RX 8                            // region x-extent  (bx = ix>>3)
#define RY 16                           // region y-extent  (by = iy>>4)
#define CHUNK 2048                      // points per scatter block (4 blk/CU)
#define PTHREADS 512
#define PPT (CHUNK / PTHREADS)          // 4 points per thread, static unroll
#define GTHREADS 1024                   // gather block size (2 blk/CU, 32 w/CU)
#define FIX 16777216.0f                 // 2^24 fixed-point scale
#define INVFIX (1.0f / 16777216.0f)

typedef float nf4 __attribute__((ext_vector_type(4)));

// Record: 8 bytes.
//   lo = fx16 | fy16<<16                        (frac, 1/65536 fixed point)
//   hi = fz16 | (lx+1)<<16 | (ly+1)<<20 | iz<<25
// lx in [-1,7] rel. to bin x-origin, ly in [-1,15] rel. to bin y-origin,
// iz = absolute z voxel (7 bits).

// -------- Single-pass scatter: LDS hist -> segment reservation -> emit -----
// 512 threads, CHUNK=2048 -> 1024 blocks -> 4 blocks/CU; launch_bounds(512,8)
// caps VGPR at 64 so all 32 waves/CU are resident (latency hiding for the
// point loads + scattered record stores). Decode is done ONCE into 12 cached
// VGPRs per thread (static unroll), Phase C emits from registers.
__global__ __launch_bounds__(PTHREADS, 8) void scatter_onepass(
    const float* __restrict__ p0, const float* __restrict__ p1,
    unsigned* __restrict__ gcnt,        // [nkeys], pre-zeroed
    uint2* __restrict__ sorted,         // [nkeys][capacity]
    int N, int B, int nchunks, unsigned capacity)
{
    __shared__ unsigned h[SBINS];
    __shared__ unsigned cur[SBINS];

    const int blk = blockIdx.x;
    const int tid = threadIdx.x;
    const int cb = blk / nchunks;            // cloud*B + batch
    const int c  = blk - cb * nchunks;
    const float* p = (cb < B ? p0 : p1) +
                     ((size_t)(cb % B) * N + (size_t)c * CHUNK) * 3;

    if (tid < SBINS) h[tid] = 0u;
    __syncthreads();

    // Phase A: decode once into registers + LDS histogram (corner-dup aware).
    unsigned rlo[PPT], rezi[PPT], rxy[PPT];
#pragma unroll
    for (int j = 0; j < PPT; ++j) {
        int i = tid + j * PTHREADS;
        float px = p[3*i+0] * 64.0f;
        float py = p[3*i+1] * 64.0f;
        float pz = p[3*i+2] * 64.0f;
        float lx = floorf(px), ly = floorf(py), lz = floorf(pz);
        int ix = (int)lx + 64, iy = (int)ly + 64, iz = (int)lz + 64;
        unsigned ex = min((unsigned)((px - lx) * 65536.0f), 65535u);
        unsigned ey = min((unsigned)((py - ly) * 65536.0f), 65535u);
        unsigned ez = min((unsigned)((pz - lz) * 65536.0f), 65535u);
        rlo[j]  = ex | (ey << 16);
        rezi[j] = ez | ((unsigned)iz << 16);
        rxy[j]  = (unsigned)ix | ((unsigned)iy << 16);
        int bx0 = ix >> 3, by0 = iy >> 4;
        int bx1 = (ix+1) >> 3, by1 = (iy+1) >> 4;
        for (int bx = bx0; bx <= bx1; ++bx)
            for (int by = by0; by <= by1; ++by)
                atomicAdd(&h[(bx << 3) + by], 1u);
    }
    __syncthreads();

    // Phase B: reserve a contiguous segment of each touched bucket.
    if (tid < SBINS)
        cur[tid] = atomicAdd(&gcnt[cb * SBINS + tid], h[tid]);
    __syncthreads();

    // Phase C: emit records from registers (no global re-read, no re-decode).
    size_t sbase = (size_t)cb * SBINS * capacity;
#pragma unroll
    for (int j = 0; j < PPT; ++j) {
        unsigned lo = rlo[j];
        unsigned ez = rezi[j] & 0xffffu;
        unsigned iz = rezi[j] >> 16;
        int ix = (int)(rxy[j] & 0xffffu);
        int iy = (int)(rxy[j] >> 16);
        int bx0 = ix >> 3, by0 = iy >> 4;
        int bx1 = (ix+1) >> 3, by1 = (iy+1) >> 4;
        for (int bx = bx0; bx <= bx1; ++bx)
            for (int by = by0; by <= by1; ++by) {
                unsigned llx = (unsigned)(ix - (bx << 3) + 1);  // [0,8]
                unsigned lly = (unsigned)(iy - (by << 4) + 1);  // [0,16]
                unsigned hi = ez | (llx << 16) | (lly << 20) | (iz << 25);
                int k = (bx << 3) + by;
                unsigned slot = atomicAdd(&cur[k], 1u);
                if (slot < capacity)
                    sorted[sbase + (size_t)k * capacity + slot] =
                        make_uint2(lo, hi);
            }
    }
}

// -------- Gather: per-slab fixed-point LDS accumulate + contiguous store ---
// One block per (cb, bx, by): 8 x 16 x 128 slab (64 KB LDS) in 24.8 fixed
// point via native ds_add_u32. 1024 threads -> 2 blocks/CU -> 32 waves/CU
// (vs 16 before): doubles the wave pool hiding the record-load latency.
// launch_bounds(1024,8) caps VGPR at 64 (body is ~45 live regs).
__global__ __launch_bounds__(GTHREADS, 8) void gather3_kernel(
    const uint2* __restrict__ sorted,
    const unsigned* __restrict__ gcnt,
    float* __restrict__ out, unsigned capacity)
{
    __shared__ unsigned acc[RX * RY * DXYZ];  // 64 KB: [cx][cy][cz]
    const int g = blockIdx.x;
    const int tid = threadIdx.x;
    const int cb = g >> 7;
    const int r = g & (SBINS - 1);
    const int rx = r >> 3, ry = r & 7;
    const int x0 = rx << 3, y0 = ry << 4;

    uint4* a4 = (uint4*)acc;
    uint4 z4 = make_uint4(0u, 0u, 0u, 0u);
    for (int i = tid; i < RX * RY * DXYZ / 4; i += GTHREADS) a4[i] = z4;
    __syncthreads();

    const float inv = 1.0f / 65536.0f;
    unsigned cnt = min(gcnt[g], capacity);
    size_t s = (size_t)g * capacity;
    for (unsigned i = tid; i < cnt; i += GTHREADS) {
        uint2 rec = sorted[s + i];
        float fx = (float)(rec.x & 0xffffu) * inv;
        float fy = (float)(rec.x >> 16) * inv;
        float fz = (float)(rec.y & 0xffffu) * inv;
        int lx = (int)((rec.y >> 16) & 15u) - 1;
        int ly = (int)((rec.y >> 20) & 31u) - 1;
        int zc = (int)(rec.y >> 25);
        float gx[2] = {1.0f - fx, fx};
        float gy[2] = {1.0f - fy, fy};
        float gz[2] = {1.0f - fz, fz};
#pragma unroll
        for (int dx = 0; dx < 2; ++dx) {
            int cx = lx + dx;
            if ((unsigned)cx >= (unsigned)RX) continue;
#pragma unroll
            for (int dy = 0; dy < 2; ++dy) {
                int cy = ly + dy;
                if ((unsigned)cy >= (unsigned)RY) continue;
#pragma unroll
                for (int dz = 0; dz < 2; ++dz) {
                    int cz = zc + dz;
                    if ((unsigned)cz >= (unsigned)DXYZ) continue;
                    unsigned w = (unsigned)(gx[dx] * gy[dy] * gz[dz]
                                            * FIX + 0.5f);
                    atomicAdd(&acc[((cx << 4) + cy) * DXYZ + cz], w);
                }
            }
        }
    }
    __syncthreads();

    // Epilogue: convert fixed->float, contiguous nontemporal float4 stores.
    // Flat index over 4096 uint4: cx = i>>9 (512 uint4 per cx-slab).
    float* ob = out + (size_t)cb * NVERT;
    for (int i = tid; i < RX * RY * DXYZ / 4; i += GTHREADS) {
        int cx = i >> 9;
        int t = i & 511;
        size_t base = (((size_t)(x0 + cx) * DXYZ) + (size_t)y0) * DXYZ;
        nf4* dst = (nf4*)(ob + base);
        const uint4* src = (const uint4*)&acc[cx * (RY * DXYZ)];
        uint4 u = src[t];
        nf4 f = {(float)u.x * INVFIX, (float)u.y * INVFIX,
                 (float)u.z * INVFIX, (float)u.w * INVFIX};
        __builtin_nontemporal_store(f, &dst[t]);
    }
}

// ---------------- Fallback: direct atomic splat ----------------
__global__ __launch_bounds__(256) void splat_kernel(
    const float* __restrict__ pts, float* __restrict__ out,
    int n_per_batch, int total)
{
    int t = blockIdx.x * blockDim.x + threadIdx.x;
    if (t >= total) return;
    float px = pts[3*t+0] * 64.0f, py = pts[3*t+1] * 64.0f, pz = pts[3*t+2] * 64.0f;
    float lx = floorf(px), ly = floorf(py), lz = floorf(pz);
    float fx = px - lx, fy = py - ly, fz = pz - lz;
    int ix = (int)lx + 64, iy = (int)ly + 64, iz = (int)lz + 64;
    int b = t / n_per_batch;
    float* o = out + (size_t)b * NVERT;
    size_t base = ((size_t)ix * DXYZ + (size_t)iy) * DXYZ + (size_t)iz;
    float gx[2] = {1.0f-fx, fx}, gy[2] = {1.0f-fy, fy}, gz[2] = {1.0f-fz, fz};
#pragma unroll
    for (int dx = 0; dx < 2; ++dx)
#pragma unroll
        for (int dy = 0; dy < 2; ++dy)
#pragma unroll
            for (int dz = 0; dz < 2; ++dz)
                atomicAdd(o + base + (size_t)dx * (DXYZ*DXYZ) + dy * DXYZ + dz,
                          gx[dx] * gy[dy] * gz[dz]);
}

static inline size_t align256(size_t x) { return (x + 255) & ~(size_t)255; }

extern "C" void kernel_launch(void* const* d_in, const int* in_sizes, int n_in,
                              void* d_out, int out_size, void* d_ws, size_t ws_size,
                              hipStream_t stream) {
    const float* pred = (const float*)d_in[0];
    const float* gt   = (const float*)d_in[1];
    float* out = (float*)d_out;

    int total = in_sizes[0] / 3;           // B*N points per cloud
    int B = out_size / (2 * NVERT);
    int N = total / B;
    int CB = 2 * B;
    int nchunks = N / CHUNK;
    int nkeys = CB * SBINS;
    int nblocks = CB * nchunks;
    bool divisible = (N % CHUNK) == 0 && N > 0;

    // Bucket capacity: 2x the dup-inflated per-key mean (E[dup]~=1.2,
    // sigma ~= sqrt(mean) -> 2x mean is a >30-sigma margin), 256-aligned.
    unsigned mean = (unsigned)(((size_t)N * 5 / 4) / SBINS);
    unsigned capacity = ((mean * 2) + 255u) & ~255u;
    if (capacity < 1024u) capacity = 1024u;

    size_t off_gcnt   = 0;
    size_t off_sorted = align256((size_t)nkeys * 4);
    size_t need = off_sorted + (size_t)nkeys * capacity * sizeof(uint2);

    if (!divisible || ws_size < need) {
        (void)hipMemsetAsync(d_out, 0, (size_t)out_size * sizeof(float), stream);
        int blocks = (total + 255) / 256;
        splat_kernel<<<blocks, 256, 0, stream>>>(pred, out, N, total);
        splat_kernel<<<blocks, 256, 0, stream>>>(gt, out + (size_t)B * NVERT, N, total);
        return;
    }

    char* ws = (char*)d_ws;
    unsigned* gcnt = (unsigned*)(ws + off_gcnt);
    uint2*    sorted = (uint2*)(ws + off_sorted);

    (void)hipMemsetAsync(gcnt, 0, (size_t)nkeys * 4, stream);
    scatter_onepass<<<nblocks, PTHREADS, 0, stream>>>(pred, gt, gcnt, sorted,
                                                      N, B, nchunks, capacity);
    gather3_kernel<<<nkeys, GTHREADS, 0, stream>>>(sorted, gcnt, out, capacity);
}